// Round 2
// baseline (416.286 us; speedup 1.0000x reference)
//
#include <hip/hip_runtime.h>
#include <cstdint>
#include <cmath>

// LQE fused: per-wave double-buffered DMA pipeline (T3/T4 counted-vmcnt).
// B=32, L=10000 -> 320000 anchors; 4 sides x 33 bins; k_top=4; HID=64; NC=80.
//
// R5: R4 (DMA + block-wide sync) serialized DMA vs compute inside each
// block and occupancy (9.4%) couldn't cover it -> 1.85 TB/s, 126 us.
// Now each block = ONE wave owning 5 consecutive 64-anchor tiles with two
// 33.8 KB LDS buffers. Counted per-wave waits (vmcnt(33)) keep the next
// tile's 33 global_load_lds in flight UNDER the current tile's compute;
// vmcnt never drains to 0 in the main loop (T4). No __syncthreads anywhere
// (single wave: cross-lane LDS is ordered by lgkmcnt in program order).
// Weights go to registers BEFORE any DMA so the vmcnt stream holds only
// tile DMAs; epilogue (20 float4 loads+stores per tile) is batched after
// the loop so its vmem ops never pollute the counted waits.

constexpr int NB   = 33;
constexpr int DPR  = 132;
constexpr int HID  = 64;
constexpr int NCLS = 80;
constexpr int APB  = 64;    // anchors per tile == blockDim.x == one wave
constexpr int TPB  = 5;     // tiles per block (5000 tiles / 1000 blocks)

#define AS_GLOBAL __attribute__((address_space(1)))
#define AS_LDS    __attribute__((address_space(3)))

__device__ __forceinline__ void dma16(const void* g, void* l) {
    // per-lane global src; LDS dest = wave-uniform base + lane*16.
    __builtin_amdgcn_global_load_lds((const AS_GLOBAL uint32_t*)g,
                                     (AS_LDS uint32_t*)l, 16, 0, 0);
}

__global__
__attribute__((amdgpu_flat_work_group_size(APB, APB), amdgpu_waves_per_eu(1, 2)))
void lqe_fused(
    const float* __restrict__ scores,
    const float* __restrict__ pred,
    const float* __restrict__ w1,
    const float* __restrict__ b1,
    const float* __restrict__ w2,
    const float* __restrict__ b2,
    float* __restrict__ out)
{
    __shared__ float s_pred[2][APB * DPR];  // 2 x 33792 B double buffer
    __shared__ float s_w1[HID * 16];        // folded: w1[j][5s+q] + .25*w1[j][5s+4]
    __shared__ float s_b1[HID];
    __shared__ float s_w2[HID];
    __shared__ float s_q[TPB][APB];         // per-tile quality for epilogue

    const int t = threadIdx.x;
    const long long tile0 = (long long)blockIdx.x * TPB;
    const long long ab0   = tile0 * APB;

    // ---- weights -> registers FIRST (their vmcnt retires before tile DMAs,
    //      in-order, so counted waits below stay exact) ----
    float wreg[20];
    {
        const float4* wsrc = (const float4*)(w1 + t * 20);
        #pragma unroll
        for (int i = 0; i < 5; ++i) ((float4*)wreg)[i] = wsrc[i];
    }
    const float b1r = b1[t];
    const float w2r = w2[t];
    const float b2r = b2[0];

    // fold mean into w1 and stage to LDS (same-wave: no barrier needed)
    #pragma unroll
    for (int s = 0; s < 4; ++s) {
        float wm = 0.25f * wreg[s * 5 + 4];
        #pragma unroll
        for (int q = 0; q < 4; ++q)
            s_w1[t * 16 + s * 4 + q] = wreg[s * 5 + q] + wm;
    }
    s_b1[t] = b1r;
    s_w2[t] = w2r;

    // ---- DMA stage: 33 x 1KB contiguous, zero VGPR round-trip ----
    auto stage = [&](int slot, long long tile) {
        const uint32_t* g = (const uint32_t*)pred + tile * (long long)(APB * DPR);
        uint32_t* l = (uint32_t*)&s_pred[slot][0];
        #pragma unroll
        for (int k = 0; k < 33; ++k)
            dma16(g + k * 256 + t * 4, l + k * 256);
    };

    // ---- per-tile compute: softmax-top4 stats + MLP -> s_q[row] ----
    auto process = [&](const float* buf, int row) {
        const float4* lp = (const float4*)(buf + t * DPR);   // 528 B stride
        float f[16];
        float e0 = 0.f, e1 = 0.f, e2 = 0.f, e3 = 0.f, sum = 0.f;
        #pragma unroll
        for (int ld = 0; ld < 33; ++ld) {
            float4 v4 = lp[ld];
            float vv[4] = {v4.x, v4.y, v4.z, v4.w};
            #pragma unroll
            for (int c = 0; c < 4; ++c) {
                const int idx = 4 * ld + c;            // compile-time
                float e = __expf(vv[c]);
                sum += e;
                // branchless top-4 insertion (exp >= 0, so 0-init == -inf)
                float n0 = fminf(e0, e);  e0 = fmaxf(e0, e);
                float n1 = fminf(e1, n0); e1 = fmaxf(e1, n0);
                float n2 = fminf(e2, n1); e2 = fmaxf(e2, n1);
                e3 = fmaxf(e3, n2);
                if (idx % NB == NB - 1) {              // side done: 32/65/98/131
                    const int s = idx / NB;
                    float inv = 1.0f / sum;
                    f[s * 4 + 0] = e0 * inv;
                    f[s * 4 + 1] = e1 * inv;
                    f[s * 4 + 2] = e2 * inv;
                    f[s * 4 + 3] = e3 * inv;
                    e0 = e1 = e2 = e3 = 0.f; sum = 0.f;
                }
            }
        }
        float qv = b2r;
        #pragma unroll
        for (int j = 0; j < HID; ++j) {
            const float4* wr = (const float4*)(s_w1 + j * 16);  // uniform bcast
            float hj = s_b1[j];
            #pragma unroll
            for (int i4 = 0; i4 < 4; ++i4) {
                float4 w = wr[i4];
                hj = fmaf(f[4 * i4 + 0], w.x, hj);
                hj = fmaf(f[4 * i4 + 1], w.y, hj);
                hj = fmaf(f[4 * i4 + 2], w.z, hj);
                hj = fmaf(f[4 * i4 + 3], w.w, hj);
            }
            hj = fmaxf(hj, 0.f);
            qv = fmaf(hj, s_w2[j], qv);
        }
        s_q[row][t] = qv;
    };

    // ---- prime the pipeline: 2 tiles (66 DMAs) in flight ----
    stage(0, tile0 + 0);
    stage(1, tile0 + 1);

    // ---- main loop: counted vmcnt, never drained to 0 until the last tile ----
    #pragma unroll
    for (int i = 0; i < TPB; ++i) {
        if (i < TPB - 1)
            asm volatile("s_waitcnt vmcnt(33)" ::: "memory");  // tile i landed
        else
            asm volatile("s_waitcnt vmcnt(0)"  ::: "memory");
        process(&s_pred[i & 1][0], i);
        asm volatile("s_waitcnt lgkmcnt(0)" ::: "memory");     // WAR fence on buf
        if (i + 2 < TPB)
            stage(i & 1, tile0 + i + 2);
    }

    // ---- epilogue: out = scores + quality; 5 x 20 coalesced float4 ----
    #pragma unroll 1
    for (int i = 0; i < TPB; ++i) {
        const long long ab = ab0 + (long long)i * APB;
        const float4* sc4 = (const float4*)(scores + ab * NCLS);
        float4*       ot4 = (float4*)(out + ab * NCLS);
        float4 v[20];
        float  q[20];
        #pragma unroll
        for (int u = 0; u < 20; ++u) {        // 20*64 = 1280 float4 / tile
            const int idx = u * APB + t;
            v[u] = sc4[idx];                  // deep in-flight, coalesced 1KB
            q[u] = s_q[i][idx / 20];          // 20 float4 per anchor
        }
        #pragma unroll
        for (int u = 0; u < 20; ++u) {
            const int idx = u * APB + t;
            float4 w = v[u];
            float qq = q[u];
            w.x += qq; w.y += qq; w.z += qq; w.w += qq;
            ot4[idx] = w;
        }
    }
}

extern "C" void kernel_launch(void* const* d_in, const int* in_sizes, int n_in,
                              void* d_out, int out_size, void* d_ws, size_t ws_size,
                              hipStream_t stream) {
    const float* scores = (const float*)d_in[0];
    const float* pred   = (const float*)d_in[1];
    const float* w1     = (const float*)d_in[2];
    const float* b1     = (const float*)d_in[3];
    const float* w2     = (const float*)d_in[4];
    const float* b2     = (const float*)d_in[5];
    // d_in[6] = k_top (==4, baked in)

    int n_anchor = in_sizes[0] / NCLS;      // 320000
    int blocks   = n_anchor / (APB * TPB);  // 1000, exact
    lqe_fused<<<blocks, APB, 0, stream>>>(scores, pred, w1, b1, w2, b2,
                                          (float*)d_out);
}

// Round 3
// 375.406 us; speedup vs baseline: 1.1089x; 1.1089x over previous
//
#include <hip/hip_runtime.h>
#include <cstdint>
#include <cmath>

// LQE split: (A) latency-optimized q-compute with forced 8-deep load ring;
// (B) pure-streaming broadcast add. B=32,L=10000 -> 320000 anchors;
// 4 sides x 33 bins; k_top=4; HID=64; NC=80.
//
// R6: R4/R5 proved per-wave gload_lds serializes (~600ns/instr) and LDS
// footprint caps DMA designs at ~2 waves/CU -> 1.2-1.8 TB/s ceiling.
// R3's reg-load version had waves (14/CU) but VGPR=44 shows the compiler
// collapsed its burst to ~1 outstanding load (per-op latency ~2800 cyc).
// Fix: inline-asm global_load_dwordx4 ring (depth 8) with hand-counted
// s_waitcnt vmcnt(7) + sched_barrier(0) (rule #18) -- the compiler cannot
// collapse asm loads, so 8 KB/wave stays in flight at ~20 waves/CU.
// The scores+q epilogue moves to a separate trivially-BW-bound kernel so
// its 200 MB runs at streaming BW with massive TLP instead of being
// serialized inside the latency-bound wave.

constexpr int NB   = 33;
constexpr int DPR  = 132;
constexpr int HID  = 64;
constexpr int NCLS = 80;

struct QState {
    float e0, e1, e2, e3, sum;
    float f[16];
};

// ---- one element-group step of the softmax/top-4 stream (idx compile-time) ----
template<int K>
__device__ __forceinline__ void qstep(float4 (&buf)[8], uint64_t addr, QState& st)
{
    constexpr int NWAIT = (K < 25) ? 7 : (32 - K);   // loads in flight after wait
    asm volatile("s_waitcnt vmcnt(%0)" :: "n"(NWAIT) : "memory");
    __builtin_amdgcn_sched_barrier(0);               // rule #18: pin consumers below
    float4 v4 = buf[K & 7];
    float vv[4] = {v4.x, v4.y, v4.z, v4.w};
    #pragma unroll
    for (int c = 0; c < 4; ++c) {
        const int idx = 4 * K + c;                   // compile-time
        float e = __expf(vv[c]);
        st.sum += e;
        // branchless top-4 insertion (exp >= 0, so 0-init == -inf)
        float n0 = fminf(st.e0, e);  st.e0 = fmaxf(st.e0, e);
        float n1 = fminf(st.e1, n0); st.e1 = fmaxf(st.e1, n0);
        float n2 = fminf(st.e2, n1); st.e2 = fmaxf(st.e2, n1);
        st.e3 = fmaxf(st.e3, n2);
        if (idx % NB == NB - 1) {                    // side done: 32/65/98/131
            const int s = idx / NB;
            float inv = 1.0f / st.sum;
            st.f[s * 4 + 0] = st.e0 * inv;
            st.f[s * 4 + 1] = st.e1 * inv;
            st.f[s * 4 + 2] = st.e2 * inv;
            st.f[s * 4 + 3] = st.e3 * inv;
            st.e0 = st.e1 = st.e2 = st.e3 = 0.f; st.sum = 0.f;
        }
    }
    if constexpr (K + 8 < 33) {                      // refill the slot just consumed
        asm volatile("global_load_dwordx4 %0, %1, off offset:%2"
                     : "=v"(buf[K & 7]) : "v"(addr), "n"(16 * (K + 8)));
    }
}

template<int K>
__device__ __forceinline__ void qsteps(float4 (&buf)[8], uint64_t addr, QState& st)
{
    qstep<K>(buf, addr, st);
    if constexpr (K < 32) qsteps<K + 1>(buf, addr, st);
}

template<int K>
__device__ __forceinline__ void qprime(float4 (&buf)[8], uint64_t addr)
{
    asm volatile("global_load_dwordx4 %0, %1, off offset:%2"
                 : "=v"(buf[K]) : "v"(addr), "n"(16 * K));
    if constexpr (K < 7) qprime<K + 1>(buf, addr);
}

// ---- kernel A: pred -> per-anchor quality q ----
__global__ __launch_bounds__(256, 5)   // VGPR budget 102; est ~85
void lqe_q(
    const float* __restrict__ pred,
    const float* __restrict__ w1,
    const float* __restrict__ b1,
    const float* __restrict__ w2,
    const float* __restrict__ b2,
    float* __restrict__ qout)
{
    __shared__ float s_w1[HID * 16];   // folded: w1[j][5s+q] + .25*w1[j][5s+4]
    __shared__ float s_b1[HID];
    __shared__ float s_w2[HID];

    const int t = threadIdx.x;
    const float b2r = b2[0];
    for (int i = t; i < HID * 16; i += 256) {
        int j = i >> 4, col = i & 15, s = col >> 2, q = col & 3;
        s_w1[i] = w1[j * 20 + s * 5 + q] + 0.25f * w1[j * 20 + s * 5 + 4];
    }
    if (t < HID) { s_b1[t] = b1[t]; s_w2[t] = w2[t]; }
    __syncthreads();                   // also drains vmcnt -> ring counts exact

    const long long a = (long long)blockIdx.x * 256 + t;
    const uint64_t addr = (uint64_t)(pred + a * (long long)DPR);  // 528B, 16B-aligned

    float4 buf[8];
    qprime<0>(buf, addr);              // 8 x 1KB in flight per wave, guaranteed

    QState st;
    st.e0 = st.e1 = st.e2 = st.e3 = st.sum = 0.f;
    qsteps<0>(buf, addr, st);

    // MLP: h_j = relu(b1_j + f . w1eff_j); qv = b2 + h . w2
    float qv = b2r;
    #pragma unroll
    for (int j = 0; j < HID; ++j) {
        const float4* wr = (const float4*)(s_w1 + j * 16);   // uniform broadcast
        float hj = s_b1[j];
        #pragma unroll
        for (int i4 = 0; i4 < 4; ++i4) {
            float4 w = wr[i4];
            hj = fmaf(st.f[4 * i4 + 0], w.x, hj);
            hj = fmaf(st.f[4 * i4 + 1], w.y, hj);
            hj = fmaf(st.f[4 * i4 + 2], w.z, hj);
            hj = fmaf(st.f[4 * i4 + 3], w.w, hj);
        }
        hj = fmaxf(hj, 0.f);
        qv = fmaf(hj, s_w2[j], qv);
    }
    qout[a] = qv;                      // coalesced dword store
}

// ---- kernel B: out = scores + q (pure streaming, max TLP) ----
__global__ __launch_bounds__(256)
void lqe_add(
    const float* __restrict__ scores,
    const float* __restrict__ qin,
    float* __restrict__ out)
{
    const int i = blockIdx.x * 256 + threadIdx.x;   // float4 index, exact grid
    const float q = qin[i / 20];                    // 20 float4 per anchor; L2-hit
    float4 v = ((const float4*)scores)[i];
    v.x += q; v.y += q; v.z += q; v.w += q;
    ((float4*)out)[i] = v;
}

extern "C" void kernel_launch(void* const* d_in, const int* in_sizes, int n_in,
                              void* d_out, int out_size, void* d_ws, size_t ws_size,
                              hipStream_t stream) {
    const float* scores = (const float*)d_in[0];
    const float* pred   = (const float*)d_in[1];
    const float* w1     = (const float*)d_in[2];
    const float* b1     = (const float*)d_in[3];
    const float* w2     = (const float*)d_in[4];
    const float* b2     = (const float*)d_in[5];
    // d_in[6] = k_top (==4, baked in)

    int n_anchor = in_sizes[0] / NCLS;       // 320000
    float* qbuf  = (float*)d_ws;             // 1.28 MB scratch

    lqe_q<<<n_anchor / 256, 256, 0, stream>>>(pred, w1, b1, w2, b2, qbuf);

    int nf4 = n_anchor * (NCLS / 4);         // 6,400,000 float4
    lqe_add<<<nf4 / 256, 256, 0, stream>>>(scores, qbuf, (float*)d_out);
}

// Round 5
// 351.915 us; speedup vs baseline: 1.1829x; 1.0668x over previous
//
#include <hip/hip_runtime.h>
#include <cstdint>
#include <cmath>

// LQE split: (A) q-compute via coalesced reg-staged LDS tiles (wave-private);
// (B) pure-streaming broadcast add. B=32, L=10000 -> 320000 anchors;
// 4 sides x 33 bins; k_top=4; HID=64; NC=80.
//
// R8 = R7 + the missing LDS fences. R7's stage->compute hand-off is
// cross-lane (lane t writes linear slices k*64+t, reads row t*33..+32 --
// other lanes' data). Without __syncthreads the compiler may reorder
// ds_read above ds_write (addresses don't alias in single-thread view):
// absmax 0.406. Hardware DS in-order is NOT a compiler contract.
// Fix: __syncthreads() after stage (RAW) and at tile end (WAR before next
// stage overwrite). Single-wave block -> barrier is ~free; the vmcnt(0)
// drain is dead cost only (loads already consumed into LDS).
//
// Perf design (unchanged from R7): global side fully coalesced (lane i <-
// base + i*16B; the 528B-lane-stride direct-load shape was TA-bound at
// ~2 TB/s in R3/R6). Anchor stride 132 floats == 4 mod 32 banks -> both
// linear ds_write and 528B-stride ds_read tile banks at the wave64-b128
// minimum; NO padding. 38.4 KB LDS -> 4 single-wave blocks/CU (one per
// SIMD); stagger of independent waves overlaps stage vs compute.

constexpr int NB   = 33;
constexpr int DPR  = 132;   // floats per anchor
constexpr int F4PA = 33;    // float4 per anchor
constexpr int HID  = 64;
constexpr int NCLS = 80;
constexpr int APT  = 64;    // anchors per tile == lanes
constexpr int TPB  = 5;     // tiles per block -> grid 1000

// ---- kernel A: pred -> per-anchor quality q ----
__global__ __attribute__((amdgpu_flat_work_group_size(64, 64)))
void lqe_q(
    const float* __restrict__ pred,
    const float* __restrict__ w1,
    const float* __restrict__ b1,
    const float* __restrict__ w2,
    const float* __restrict__ b2,
    float* __restrict__ qout)
{
    __shared__ float4 s_buf[APT * F4PA];   // 33792 B, anchor-major, NO pad
    __shared__ float  s_w1[HID * 16];      // folded: w1[j][5s+q] + .25*w1[j][5s+4]
    __shared__ float  s_b1[HID];
    __shared__ float  s_w2[HID];

    const int t = threadIdx.x;             // 0..63

    // ---- fold weights: thread t owns hidden row t ----
    {
        float wr[20];
        const float4* ws = (const float4*)(w1 + t * 20);   // 80B: 16B-aligned
        #pragma unroll
        for (int i = 0; i < 5; ++i) ((float4*)wr)[i] = ws[i];
        #pragma unroll
        for (int s = 0; s < 4; ++s) {
            float wm = 0.25f * wr[s * 5 + 4];
            #pragma unroll
            for (int q = 0; q < 4; ++q)
                s_w1[t * 16 + s * 4 + q] = wr[s * 5 + q] + wm;
        }
        s_b1[t] = b1[t];
        s_w2[t] = w2[t];
    }
    const float b2r = b2[0];
    __syncthreads();                       // weights visible to all lanes

    const long long tile0 = (long long)blockIdx.x * TPB;

    for (int i = 0; i < TPB; ++i) {
        const long long tile = tile0 + i;
        const float4* g4 = (const float4*)pred + tile * (APT * F4PA);

        // ---- stage: 33 coalesced float4 copies (identity layout:
        //      linear float4 idx = anchor*33 + col). 8-deep reg batches. ----
        #pragma unroll
        for (int g = 0; g < 4; ++g) {
            float4 r[8];
            #pragma unroll
            for (int j = 0; j < 8; ++j) r[j] = g4[(g * 8 + j) * 64 + t];
            #pragma unroll
            for (int j = 0; j < 8; ++j) s_buf[(g * 8 + j) * 64 + t] = r[j];
        }
        { float4 r = g4[32 * 64 + t]; s_buf[32 * 64 + t] = r; }

        __syncthreads();    // RAW fence: other lanes' writes -> my reads

        // ---- compute: softmax-top4 stats from this lane's anchor row ----
        const float4* lp = (const float4*)s_buf + t * F4PA;   // 528 B stride
        float f[16];
        float e0 = 0.f, e1 = 0.f, e2 = 0.f, e3 = 0.f, sum = 0.f;
        #pragma unroll
        for (int ld = 0; ld < 33; ++ld) {
            float4 v4 = lp[ld];
            float vv[4] = {v4.x, v4.y, v4.z, v4.w};
            #pragma unroll
            for (int c = 0; c < 4; ++c) {
                const int idx = 4 * ld + c;            // compile-time
                float e = __expf(vv[c]);
                sum += e;
                // branchless top-4 insertion (exp >= 0, so 0-init == -inf)
                float n0 = fminf(e0, e);  e0 = fmaxf(e0, e);
                float n1 = fminf(e1, n0); e1 = fmaxf(e1, n0);
                float n2 = fminf(e2, n1); e2 = fmaxf(e2, n1);
                e3 = fmaxf(e3, n2);
                if (idx % NB == NB - 1) {              // side done: 32/65/98/131
                    const int s = idx / NB;
                    float inv = 1.0f / sum;
                    f[s * 4 + 0] = e0 * inv;
                    f[s * 4 + 1] = e1 * inv;
                    f[s * 4 + 2] = e2 * inv;
                    f[s * 4 + 3] = e3 * inv;
                    e0 = e1 = e2 = e3 = 0.f; sum = 0.f;
                }
            }
        }

        // ---- MLP: h_j = relu(b1_j + f . w1eff_j); qv = b2 + h . w2 ----
        float qv = b2r;
        #pragma unroll
        for (int j = 0; j < HID; ++j) {
            const float4* wr = (const float4*)(s_w1 + j * 16);  // uniform bcast
            float hj = s_b1[j];
            #pragma unroll
            for (int i4 = 0; i4 < 4; ++i4) {
                float4 w = wr[i4];
                hj = fmaf(f[4 * i4 + 0], w.x, hj);
                hj = fmaf(f[4 * i4 + 1], w.y, hj);
                hj = fmaf(f[4 * i4 + 2], w.z, hj);
                hj = fmaf(f[4 * i4 + 3], w.w, hj);
            }
            hj = fmaxf(hj, 0.f);
            qv = fmaf(hj, s_w2[j], qv);
        }
        qout[tile * APT + t] = qv;         // coalesced 256B store

        __syncthreads();    // WAR fence: my reads done before next stage writes
    }
}

// ---- kernel B: out = scores + q (pure streaming, max TLP) ----
__global__ __launch_bounds__(256)
void lqe_add(
    const float* __restrict__ scores,
    const float* __restrict__ qin,
    float* __restrict__ out)
{
    const int i = blockIdx.x * 256 + threadIdx.x;   // float4 index, exact grid
    const float q = qin[i / 20];                    // 20 float4 per anchor; L2-hit
    float4 v = ((const float4*)scores)[i];
    v.x += q; v.y += q; v.z += q; v.w += q;
    ((float4*)out)[i] = v;
}

extern "C" void kernel_launch(void* const* d_in, const int* in_sizes, int n_in,
                              void* d_out, int out_size, void* d_ws, size_t ws_size,
                              hipStream_t stream) {
    const float* scores = (const float*)d_in[0];
    const float* pred   = (const float*)d_in[1];
    const float* w1     = (const float*)d_in[2];
    const float* b1     = (const float*)d_in[3];
    const float* w2     = (const float*)d_in[4];
    const float* b2     = (const float*)d_in[5];
    // d_in[6] = k_top (==4, baked in)

    int n_anchor = in_sizes[0] / NCLS;       // 320000
    float* qbuf  = (float*)d_ws;             // 1.28 MB scratch

    lqe_q<<<n_anchor / (APT * TPB), APT, 0, stream>>>(pred, w1, b1, w2, b2, qbuf);

    int nf4 = n_anchor * (NCLS / 4);         // 6,400,000 float4
    lqe_add<<<nf4 / 256, 256, 0, stream>>>(scores, qbuf, (float*)d_out);
}